// Round 1
// 163.049 us; speedup vs baseline: 1.0423x; 1.0423x over previous
//
#include <hip/hip_runtime.h>
#include <stdint.h>

#define EPS 1e-8f

constexpr int HW = 16384;   // pixels per image (M and N dims)
constexpr int BM = 128;     // block M tile
constexpr int NG = 2048;    // n-group width per block (32 q-substeps of 64)

typedef __attribute__((ext_vector_type(4))) float floatx4;
typedef __attribute__((ext_vector_type(8))) int   intx8;    // 32B = one f8f6f4 K=128 operand
typedef unsigned char u8;
typedef unsigned int u32;
typedef unsigned long long u64;

// HW packed fp8 e4m3 convert: 4 floats -> 4 bytes (2x v_cvt_pk_fp8_f32)
__device__ inline u32 pk4(float x0, float x1, float x2, float x3) {
    int t = __builtin_amdgcn_cvt_pk_fp8_f32(x0, x1, 0, false);
    t = __builtin_amdgcn_cvt_pk_fp8_f32(x2, x3, t, true);
    return (u32)t;
}

__device__ inline float getc(const float4& f, int j) {
    return (j == 0) ? f.x : (j == 1) ? f.y : (j == 2) ? f.z : f.w;
}

// ---------------------------------------------------------------------------
// PREP: one pass over a,b -> sumsq_a/b + fp8 fragment arrays (MX K=128 layout).
// Fragment layout for mfma_scale_f32_16x16x128_f8f6f4: pixel p, channel c:
//   g = p>>4 (16-px slab), r = p&15, kb = c>>7, q = (c>>5)&3, e = c&31
//   byte offset = (g*2+kb)*2048 + (q*16 + r)*32 + e      (lane = q*16+r, k = q*32+e)
// Thread (pg=tid&15, tc=tid>>4): pixels pg*4..+3 (float4), channels tc*16..+15.
// For fixed (tc, pixel) all 16 channels land in ONE (kb,q) block at bytes
// (tc&1)*16..+15 -> a single int4 store. b normalized, a raw.
__global__ __launch_bounds__(256) void prep_kernel(const float* __restrict__ a,
                                                   const float* __restrict__ b,
                                                   float* __restrict__ sumsq_a,
                                                   float* __restrict__ sumsq_b,
                                                   u8* __restrict__ aF, u8* __restrict__ bF) {
    __shared__ float red[16][65];
    __shared__ float invb_sh[64];
    const int tid = threadIdx.x;
    const int pg = tid & 15, tc = tid >> 4;
    const int p0 = blockIdx.x * 64, pb = pg * 4;
    const int kb = tc >> 3, qg = (tc >> 1) & 3, lo16 = (tc & 1) * 16;

    // ---- b: 16 channels x 4 pixels into regs + per-pixel partial sumsq
    float4 bv[16];
    float ss0 = 0.f, ss1 = 0.f, ss2 = 0.f, ss3 = 0.f;
    #pragma unroll
    for (int i = 0; i < 16; ++i) {
        bv[i] = *(const float4*)&b[(size_t)(tc * 16 + i) * HW + p0 + pb];
        ss0 += bv[i].x * bv[i].x; ss1 += bv[i].y * bv[i].y;
        ss2 += bv[i].z * bv[i].z; ss3 += bv[i].w * bv[i].w;
    }
    red[tc][pb] = ss0; red[tc][pb + 1] = ss1; red[tc][pb + 2] = ss2; red[tc][pb + 3] = ss3;
    __syncthreads();
    if (tid < 64) {
        float B = 0.f;
        #pragma unroll
        for (int j = 0; j < 16; ++j) B += red[j][tid];
        sumsq_b[p0 + tid] = B;
        invb_sh[tid] = 1.0f / (sqrtf(B + EPS) + EPS);
    }
    __syncthreads();

    // ---- b fragment stores (normalized), one int4 per pixel
    #pragma unroll
    for (int j = 0; j < 4; ++j) {
        const int p = p0 + pb + j;
        const int g = p >> 4, rp = (pb + j) & 15;
        const float inv = invb_sh[pb + j];
        int4 W;
        W.x = (int)pk4(getc(bv[0], j) * inv, getc(bv[1], j) * inv, getc(bv[2], j) * inv, getc(bv[3], j) * inv);
        W.y = (int)pk4(getc(bv[4], j) * inv, getc(bv[5], j) * inv, getc(bv[6], j) * inv, getc(bv[7], j) * inv);
        W.z = (int)pk4(getc(bv[8], j) * inv, getc(bv[9], j) * inv, getc(bv[10], j) * inv, getc(bv[11], j) * inv);
        W.w = (int)pk4(getc(bv[12], j) * inv, getc(bv[13], j) * inv, getc(bv[14], j) * inv, getc(bv[15], j) * inv);
        *(int4*)(bF + (((size_t)(g * 2 + kb)) << 11) + (qg * 16 + rp) * 32 + lo16) = W;
    }

    // ---- a: load, raw fragments + sumsq partials
    float4 av[16];
    ss0 = ss1 = ss2 = ss3 = 0.f;
    #pragma unroll
    for (int i = 0; i < 16; ++i) {
        av[i] = *(const float4*)&a[(size_t)(tc * 16 + i) * HW + p0 + pb];
        ss0 += av[i].x * av[i].x; ss1 += av[i].y * av[i].y;
        ss2 += av[i].z * av[i].z; ss3 += av[i].w * av[i].w;
    }
    #pragma unroll
    for (int j = 0; j < 4; ++j) {
        const int p = p0 + pb + j;
        const int g = p >> 4, rp = (pb + j) & 15;
        int4 W;
        W.x = (int)pk4(getc(av[0], j), getc(av[1], j), getc(av[2], j), getc(av[3], j));
        W.y = (int)pk4(getc(av[4], j), getc(av[5], j), getc(av[6], j), getc(av[7], j));
        W.z = (int)pk4(getc(av[8], j), getc(av[9], j), getc(av[10], j), getc(av[11], j));
        W.w = (int)pk4(getc(av[12], j), getc(av[13], j), getc(av[14], j), getc(av[15], j));
        *(int4*)(aF + (((size_t)(g * 2 + kb)) << 11) + (qg * 16 + rp) * 32 + lo16) = W;
    }
    red[tc][pb] = ss0; red[tc][pb + 1] = ss1; red[tc][pb + 2] = ss2; red[tc][pb + 3] = ss3;
    __syncthreads();
    if (tid < 64) {
        float A = 0.f;
        #pragma unroll
        for (int j = 0; j < 16; ++j) A += red[j][tid];
        sumsq_a[p0 + tid] = A;
    }
}

// ---------------------------------------------------------------------------
// G: fused GEMM + argmax, MX-scaled fp8 (unit scales 0x7F -> exact same math
// as non-scaled fp8, ~2x the rate). Wave tile 64x32 (2m x 2n waves).
// Per qt: 2 K=128 phases x (4mi x 2ni) mfma_scale; C-operand of phase 0 is
// {64,64,64,64} -> acc = s+64 > 0, no per-qt zeroing. Argmax: u64 pack
// {bits(s+64), ~q} compared with a single v_max_f64 per element (positive-f64
// ordering == u64 ordering; low word breaks ties toward smallest q).
// Regs ~185 -> 2 waves/SIMD; MX MFMA (~34 SIMD-cyc each) dominates VALU.
__global__ __launch_bounds__(256, 2) void gemm_argmax(const u8* __restrict__ aF,
                                                      const u8* __restrict__ bF,
                                                      u64* __restrict__ packed) {
    const int tid = threadIdx.x;
    const int w = tid >> 6, lane = tid & 63;
    const int q4 = lane >> 4, r15 = lane & 15;
    const int wm = w >> 1, wn = w & 1;

    const u32 bid = blockIdx.x;
    const u32 ng = bid & 7;          // n-group -> XCD (L2-resident B)
    const u32 mt = bid >> 3;         // 0..127 M tile
    const int p0 = (int)mt * BM;

    // A fragments resident: slab g = mt*8 + wm*4 + mi, frag = (g*2+kb)*2048 + lane*32
    const u8* gA = aF + (((size_t)(mt * 8 + wm * 4)) << 12) + (u32)lane * 32;
    intx8 Afr[4][2];
    #pragma unroll
    for (int mi = 0; mi < 4; ++mi)
        #pragma unroll
        for (int kb = 0; kb < 2; ++kb)
            Afr[mi][kb] = *(const intx8*)(gA + (u32)(mi * 2 + kb) * 2048u);

    // B: col-group gq = ng*128 + qt*4 + wn*2 + ni; offsets qt*16384 + ni*4096 + kb*2048
    const u8* gB = bF + (((size_t)(ng * 128 + wn * 2)) << 12) + (u32)lane * 32;

    double best[4][4];
    #pragma unroll
    for (int mi = 0; mi < 4; ++mi)
        #pragma unroll
        for (int r = 0; r < 4; ++r) best[mi][r] = 0.0;

    const u32 qlane = ng * 2048 + wn * 32 + (u32)r15;   // + qt*64 + ni*16
    const floatx4 C64 = {64.f, 64.f, 64.f, 64.f};
    const int SCL = 0x7F7F7F7F;      // E8M0 127 = 2^0 in every byte -> unit scale

    intx8 Bfr[2][2];                 // [kb-buffer][ni]
    #pragma unroll
    for (int ni = 0; ni < 2; ++ni)
        Bfr[0][ni] = *(const intx8*)(gB + (u32)ni * 4096u);

    for (int qt = 0; qt < 32; ++qt) {
        const u32 qo = (u32)qt * 16384u;
        floatx4 acc[4][2];
        // phase 0: prefetch kb=1, compute kb=0 with C = bias 64
        #pragma unroll
        for (int ni = 0; ni < 2; ++ni)
            Bfr[1][ni] = *(const intx8*)(gB + qo + (u32)ni * 4096u + 2048u);
        #pragma unroll
        for (int mi = 0; mi < 4; ++mi)
            #pragma unroll
            for (int ni = 0; ni < 2; ++ni)
                acc[mi][ni] = __builtin_amdgcn_mfma_scale_f32_16x16x128_f8f6f4(
                    Afr[mi][0], Bfr[0][ni], C64, 0, 0, 0, SCL, 0, SCL);
        // phase 1: prefetch (qt+1, kb=0), compute kb=1 (accumulate)
        const u32 nqo = (qt + 1 < 32) ? qo + 16384u : qo;
        #pragma unroll
        for (int ni = 0; ni < 2; ++ni)
            Bfr[0][ni] = *(const intx8*)(gB + nqo + (u32)ni * 4096u);
        #pragma unroll
        for (int mi = 0; mi < 4; ++mi)
            #pragma unroll
            for (int ni = 0; ni < 2; ++ni)
                acc[mi][ni] = __builtin_amdgcn_mfma_scale_f32_16x16x128_f8f6f4(
                    Afr[mi][1], Bfr[1][ni], acc[mi][ni], 0, 0, 0, SCL, 0, SCL);

        // running argmax: single v_max_f64 per element (exact, smallest-q ties)
        const u32 lo0 = 0xFFFFFFFFu - (qlane + (u32)qt * 64u);
        #pragma unroll
        for (int mi = 0; mi < 4; ++mi)
            #pragma unroll
            for (int ni = 0; ni < 2; ++ni) {
                const u32 lw = lo0 - (u32)(ni * 16);
                #pragma unroll
                for (int r = 0; r < 4; ++r) {
                    u64 pk = ((u64)__float_as_uint(acc[mi][ni][r]) << 32) | (u64)lw;
                    best[mi][r] = fmax(best[mi][r], __longlong_as_double((long long)pk));
                }
            }
    }

    // final: shuffle-reduce over r15 (stays in q4 group), 1 atomic/row/wave
    #pragma unroll
    for (int mi = 0; mi < 4; ++mi)
        #pragma unroll
        for (int r = 0; r < 4; ++r) {
            u64 pk = (u64)__double_as_longlong(best[mi][r]);
            #pragma unroll
            for (int d = 1; d < 16; d <<= 1) {
                u64 o = __shfl_xor((unsigned long long)pk, d);
                pk = o > pk ? o : pk;
            }
            if (r15 == 0)
                atomicMax(&packed[p0 + wm * 64 + mi * 16 + q4 * 4 + r], pk);
        }
}

// ---------------------------------------------------------------------------
// L: loss from the argmax's own similarity value (no gather).
// Decode: hi = bits(s+64) -> s = asfloat(hi) - 64; lo = ~q.
__global__ void loss_kernel(const u64* __restrict__ packed,
                            const float* __restrict__ sumsq_a, const float* __restrict__ sumsq_b,
                            float* __restrict__ out) {
    int p = blockIdx.x * 256 + threadIdx.x;
    u64 pk = packed[p];
    float s = __uint_as_float((u32)(pk >> 32)) - 64.0f;
    u32 q = 0xFFFFFFFFu - (u32)(pk & 0xFFFFFFFFull);
    float A = sumsq_a[p], B = sumsq_b[q];
    float dot = s * (sqrtf(B + EPS) + EPS);
    float cossim = dot / ((sqrtf(A) + EPS) * (sqrtf(B) + EPS));
    float v = (1.0f - cossim) * (1.0f / (float)HW);
    #pragma unroll
    for (int d = 1; d < 64; d <<= 1) v += __shfl_xor(v, d);
    if ((threadIdx.x & 63) == 0) atomicAdd(out, v);
}

// ---------------------------------------------------------------------------
extern "C" void kernel_launch(void* const* d_in, const int* in_sizes, int n_in,
                              void* d_out, int out_size, void* d_ws, size_t ws_size,
                              hipStream_t stream) {
    const float* a = (const float*)d_in[0];
    const float* b = (const float*)d_in[1];
    float* out = (float*)d_out;
    char* ws = (char*)d_ws;

    u8*    aF      = (u8*)ws;                                    // 4 MB
    u8*    bF      = (u8*)(ws + (size_t)4 * 1024 * 1024);        // 4 MB
    float* sumsq_a = (float*)(ws + (size_t)8 * 1024 * 1024);     // 64 KB
    float* sumsq_b = sumsq_a + HW;
    u64*   packed  = (u64*)(sumsq_b + HW);                       // 128 KB

    hipMemsetAsync(out, 0, sizeof(float), stream);
    hipMemsetAsync(packed, 0, (size_t)HW * sizeof(u64), stream);

    prep_kernel<<<dim3(HW / 64), 256, 0, stream>>>(a, b, sumsq_a, sumsq_b, aF, bF);
    gemm_argmax<<<dim3((HW / BM) * (HW / NG)), 256, 0, stream>>>(aF, bF, packed);
    loss_kernel<<<dim3(HW / 256), 256, 0, stream>>>(packed, sumsq_a, sumsq_b, out);
}

// Round 2
// 156.584 us; speedup vs baseline: 1.0854x; 1.0413x over previous
//
#include <hip/hip_runtime.h>
#include <stdint.h>

#define EPS 1e-8f

constexpr int HW = 16384;   // pixels per image (M and N dims)
constexpr int BM = 128;     // block M tile
constexpr int NG = 2048;    // n-group width per block (32 q-substeps of 64)

typedef __attribute__((ext_vector_type(4))) float floatx4;
typedef __attribute__((ext_vector_type(8))) int   intx8;    // 32B = one f8f6f4 K=128 operand
typedef unsigned char u8;
typedef unsigned int u32;
typedef unsigned long long u64;

// HW packed fp8 e4m3 convert: 4 floats -> 4 bytes (2x v_cvt_pk_fp8_f32)
__device__ inline u32 pk4(float x0, float x1, float x2, float x3) {
    int t = __builtin_amdgcn_cvt_pk_fp8_f32(x0, x1, 0, false);
    t = __builtin_amdgcn_cvt_pk_fp8_f32(x2, x3, t, true);
    return (u32)t;
}

__device__ inline float getc(const float4& f, int j) {
    return (j == 0) ? f.x : (j == 1) ? f.y : (j == 2) ? f.z : f.w;
}

// ---------------------------------------------------------------------------
// PREP: 512 blocks x 32 pixels (2 blocks/CU for latency hiding).
// Thread (pg = tid&7, tc = tid>>3) covers pixels pg*4..+3 (float4) x channels
// tc*8..+7. MX K=128 fragment layout: pixel p, channel c:
//   g = p>>4, r = p&15, kb = c>>7, q = (c>>5)&3, e = c&31
//   byte = (g*2+kb)*2048 + (q*16+r)*32 + e
// For fixed (tc, pixel) the 8 channels are one aligned u64 at (tc&3)*8.
__global__ __launch_bounds__(256) void prep_kernel(const float* __restrict__ a,
                                                   const float* __restrict__ b,
                                                   float* __restrict__ sumsq_a,
                                                   float* __restrict__ sumsq_b,
                                                   u8* __restrict__ aF, u8* __restrict__ bF) {
    __shared__ float red[32][33];
    __shared__ float invb_sh[32];
    const int tid = threadIdx.x;
    const int pg = tid & 7, tc = tid >> 3;
    const int p0 = blockIdx.x * 32, pb = pg * 4;
    const int kb = tc >> 4, qg = (tc >> 2) & 3, e0 = (tc & 3) * 8;

    // ---- b: 8 channels x 4 pixels into regs + per-pixel partial sumsq
    float4 bv[8];
    float ss0 = 0.f, ss1 = 0.f, ss2 = 0.f, ss3 = 0.f;
    #pragma unroll
    for (int i = 0; i < 8; ++i) {
        bv[i] = *(const float4*)&b[(size_t)(tc * 8 + i) * HW + p0 + pb];
        ss0 += bv[i].x * bv[i].x; ss1 += bv[i].y * bv[i].y;
        ss2 += bv[i].z * bv[i].z; ss3 += bv[i].w * bv[i].w;
    }
    red[tc][pb] = ss0; red[tc][pb + 1] = ss1; red[tc][pb + 2] = ss2; red[tc][pb + 3] = ss3;
    __syncthreads();
    if (tid < 32) {
        float B = 0.f;
        #pragma unroll
        for (int j = 0; j < 32; ++j) B += red[j][tid];
        sumsq_b[p0 + tid] = B;
        invb_sh[tid] = 1.0f / (sqrtf(B + EPS) + EPS);
    }
    __syncthreads();

    // ---- b fragment stores (normalized), one u64 per pixel
    #pragma unroll
    for (int j = 0; j < 4; ++j) {
        const int p = p0 + pb + j;
        const int g = p >> 4, rp = p & 15;
        const float inv = invb_sh[pb + j];
        u64 wv = (u64)pk4(getc(bv[0], j) * inv, getc(bv[1], j) * inv,
                          getc(bv[2], j) * inv, getc(bv[3], j) * inv)
               | ((u64)pk4(getc(bv[4], j) * inv, getc(bv[5], j) * inv,
                           getc(bv[6], j) * inv, getc(bv[7], j) * inv) << 32);
        *(u64*)(bF + (((size_t)(g * 2 + kb)) << 11) + (qg * 16 + rp) * 32 + e0) = wv;
    }

    // ---- a: load, raw fragments + sumsq partials
    float4 av[8];
    ss0 = ss1 = ss2 = ss3 = 0.f;
    #pragma unroll
    for (int i = 0; i < 8; ++i) {
        av[i] = *(const float4*)&a[(size_t)(tc * 8 + i) * HW + p0 + pb];
        ss0 += av[i].x * av[i].x; ss1 += av[i].y * av[i].y;
        ss2 += av[i].z * av[i].z; ss3 += av[i].w * av[i].w;
    }
    #pragma unroll
    for (int j = 0; j < 4; ++j) {
        const int p = p0 + pb + j;
        const int g = p >> 4, rp = p & 15;
        u64 wv = (u64)pk4(getc(av[0], j), getc(av[1], j), getc(av[2], j), getc(av[3], j))
               | ((u64)pk4(getc(av[4], j), getc(av[5], j), getc(av[6], j), getc(av[7], j)) << 32);
        *(u64*)(aF + (((size_t)(g * 2 + kb)) << 11) + (qg * 16 + rp) * 32 + e0) = wv;
    }
    red[tc][pb] = ss0; red[tc][pb + 1] = ss1; red[tc][pb + 2] = ss2; red[tc][pb + 3] = ss3;
    __syncthreads();
    if (tid < 32) {
        float A = 0.f;
        #pragma unroll
        for (int j = 0; j < 32; ++j) A += red[j][tid];
        sumsq_a[p0 + tid] = A;
    }
}

// ---------------------------------------------------------------------------
// G: fused GEMM + argmax, MX-scaled fp8 (unit scales). Wave tile 64x32
// (2m x 2n waves). Per qt: 4 phases of {prefetch next 32B B operand, 4 mfma};
// phase-0/1 mfmas take C = {64,...} (positive acc, no zeroing). Argmax:
// 3-op f32 (max + cmp + cndmask), ascending scan keeps smallest q on ties.
// Regs ~163 (Afr 64 + acc 32 + best 32 + Bring 16 + misc) -> 3 waves/SIMD
// (R1 post-mortem: 2 waves left MfmaUtil at 32%; occupancy is the lever).
__global__ __launch_bounds__(256, 3) void gemm_argmax(const u8* __restrict__ aF,
                                                      const u8* __restrict__ bF,
                                                      u64* __restrict__ packed) {
    const int tid = threadIdx.x;
    const int w = tid >> 6, lane = tid & 63;
    const int q4 = lane >> 4, r15 = lane & 15;
    const int wm = w >> 1, wn = w & 1;

    const u32 bid = blockIdx.x;
    const u32 ng = bid & 7;          // n-group -> XCD (L2-resident B)
    const u32 mt = bid >> 3;         // 0..127 M tile
    const int p0 = (int)mt * BM;

    // A fragments resident: slab g = mt*8 + wm*4 + mi, frag = (g*2+kb)*2048 + lane*32
    const u8* gA = aF + (((size_t)(mt * 8 + wm * 4)) << 12) + (u32)lane * 32;
    intx8 Afr[4][2];
    #pragma unroll
    for (int mi = 0; mi < 4; ++mi)
        #pragma unroll
        for (int kb = 0; kb < 2; ++kb)
            Afr[mi][kb] = *(const intx8*)(gA + (u32)(mi * 2 + kb) * 2048u);

    // B: col-group gq = ng*128 + qt*4 + wn*2 + ni; offset gq*4096 + kb*2048
    // per-qt phase offsets: P0(ni0,kb0)=0 P1(ni1,kb0)=4096 P2(ni0,kb1)=2048 P3(ni1,kb1)=6144
    const u8* gB = bF + (((size_t)(ng * 128 + wn * 2)) << 12) + (u32)lane * 32;

    float bestv[4][4];
    u32   bestq[4][4];
    #pragma unroll
    for (int mi = 0; mi < 4; ++mi)
        #pragma unroll
        for (int r = 0; r < 4; ++r) { bestv[mi][r] = -3.4e38f; bestq[mi][r] = 0; }

    u32 q0 = ng * 2048 + wn * 32 + (u32)r15;   // running col id (ni0); ni1 = +16
    const floatx4 C64 = {64.f, 64.f, 64.f, 64.f};
    const int SCL = 0x7F7F7F7F;      // E8M0 127 = 2^0 in every byte -> unit scale

    intx8 B0 = *(const intx8*)gB;    // P0 of qt 0
    intx8 B1;

    for (int qt = 0; qt < 32; ++qt) {
        const u8* gq = gB + (u32)qt * 16384u;
        floatx4 acc[4][2];

        B1 = *(const intx8*)(gq + 4096u);                 // P1
        __builtin_amdgcn_s_setprio(1);
        #pragma unroll
        for (int mi = 0; mi < 4; ++mi)
            acc[mi][0] = __builtin_amdgcn_mfma_scale_f32_16x16x128_f8f6f4(
                Afr[mi][0], B0, C64, 0, 0, 0, SCL, 0, SCL);
        __builtin_amdgcn_s_setprio(0);

        B0 = *(const intx8*)(gq + 2048u);                 // P2
        __builtin_amdgcn_s_setprio(1);
        #pragma unroll
        for (int mi = 0; mi < 4; ++mi)
            acc[mi][1] = __builtin_amdgcn_mfma_scale_f32_16x16x128_f8f6f4(
                Afr[mi][0], B1, C64, 0, 0, 0, SCL, 0, SCL);
        __builtin_amdgcn_s_setprio(0);

        B1 = *(const intx8*)(gq + 6144u);                 // P3
        __builtin_amdgcn_s_setprio(1);
        #pragma unroll
        for (int mi = 0; mi < 4; ++mi)
            acc[mi][0] = __builtin_amdgcn_mfma_scale_f32_16x16x128_f8f6f4(
                Afr[mi][1], B0, acc[mi][0], 0, 0, 0, SCL, 0, SCL);
        __builtin_amdgcn_s_setprio(0);

        B0 = *(const intx8*)(gB + (u32)((qt + 1) & 31) * 16384u);   // next-qt P0 (wrap: dead read)
        __builtin_amdgcn_s_setprio(1);
        #pragma unroll
        for (int mi = 0; mi < 4; ++mi)
            acc[mi][1] = __builtin_amdgcn_mfma_scale_f32_16x16x128_f8f6f4(
                Afr[mi][1], B1, acc[mi][1], 0, 0, 0, SCL, 0, SCL);
        __builtin_amdgcn_s_setprio(0);

        // running argmax (ascending q scan, strict > keeps first = smallest q)
        #pragma unroll
        for (int mi = 0; mi < 4; ++mi)
            #pragma unroll
            for (int r = 0; r < 4; ++r) {
                float v = acc[mi][0][r];
                bool gt = v > bestv[mi][r];
                bestv[mi][r] = gt ? v : bestv[mi][r];
                bestq[mi][r] = gt ? q0 : bestq[mi][r];
            }
        #pragma unroll
        for (int mi = 0; mi < 4; ++mi)
            #pragma unroll
            for (int r = 0; r < 4; ++r) {
                float v = acc[mi][1][r];
                bool gt = v > bestv[mi][r];
                bestv[mi][r] = gt ? v : bestv[mi][r];
                bestq[mi][r] = gt ? (q0 + 16u) : bestq[mi][r];
            }
        q0 += 64u;
    }

    // final: pack (acc = s+64 > 0 -> float bits are monotone as uint),
    // shuffle-reduce over r15 (stays in q4 group), 1 atomic/row/wave
    #pragma unroll
    for (int mi = 0; mi < 4; ++mi)
        #pragma unroll
        for (int r = 0; r < 4; ++r) {
            u64 pk = ((u64)__float_as_uint(bestv[mi][r]) << 32)
                   | (u64)(0xFFFFFFFFu - bestq[mi][r]);
            #pragma unroll
            for (int d = 1; d < 16; d <<= 1) {
                u64 o = __shfl_xor((unsigned long long)pk, d);
                pk = o > pk ? o : pk;
            }
            if (r15 == 0)
                atomicMax(&packed[p0 + wm * 64 + mi * 16 + q4 * 4 + r], pk);
        }
}

// ---------------------------------------------------------------------------
// L: loss from the argmax's own similarity value (no gather).
// Decode: hi = bits(s+64) -> s = asfloat(hi) - 64; lo = ~q.
__global__ void loss_kernel(const u64* __restrict__ packed,
                            const float* __restrict__ sumsq_a, const float* __restrict__ sumsq_b,
                            float* __restrict__ out) {
    int p = blockIdx.x * 256 + threadIdx.x;
    u64 pk = packed[p];
    float s = __uint_as_float((u32)(pk >> 32)) - 64.0f;
    u32 q = 0xFFFFFFFFu - (u32)(pk & 0xFFFFFFFFull);
    float A = sumsq_a[p], B = sumsq_b[q];
    float dot = s * (sqrtf(B + EPS) + EPS);
    float cossim = dot / ((sqrtf(A) + EPS) * (sqrtf(B) + EPS));
    float v = (1.0f - cossim) * (1.0f / (float)HW);
    #pragma unroll
    for (int d = 1; d < 64; d <<= 1) v += __shfl_xor(v, d);
    if ((threadIdx.x & 63) == 0) atomicAdd(out, v);
}

// ---------------------------------------------------------------------------
extern "C" void kernel_launch(void* const* d_in, const int* in_sizes, int n_in,
                              void* d_out, int out_size, void* d_ws, size_t ws_size,
                              hipStream_t stream) {
    const float* a = (const float*)d_in[0];
    const float* b = (const float*)d_in[1];
    float* out = (float*)d_out;
    char* ws = (char*)d_ws;

    u8*    aF      = (u8*)ws;                                    // 4 MB
    u8*    bF      = (u8*)(ws + (size_t)4 * 1024 * 1024);        // 4 MB
    float* sumsq_a = (float*)(ws + (size_t)8 * 1024 * 1024);     // 64 KB
    float* sumsq_b = sumsq_a + HW;
    u64*   packed  = (u64*)(sumsq_b + HW);                       // 128 KB

    hipMemsetAsync(out, 0, sizeof(float), stream);
    hipMemsetAsync(packed, 0, (size_t)HW * sizeof(u64), stream);

    prep_kernel<<<dim3(HW / 32), 256, 0, stream>>>(a, b, sumsq_a, sumsq_b, aF, bF);
    gemm_argmax<<<dim3((HW / BM) * (HW / NG)), 256, 0, stream>>>(aF, bF, packed);
    loss_kernel<<<dim3(HW / 256), 256, 0, stream>>>(packed, sumsq_a, sumsq_b, out);
}

// Round 4
// 145.344 us; speedup vs baseline: 1.1693x; 1.0773x over previous
//
#include <hip/hip_runtime.h>
#include <stdint.h>

#define EPS 1e-8f

constexpr int HW = 16384;   // pixels per image (M and N dims)
constexpr int BM = 128;     // block M tile
constexpr int NG = 2048;    // n-group width per block (32 q-substeps of 64)

typedef __attribute__((ext_vector_type(4))) float floatx4;
typedef __attribute__((ext_vector_type(4))) int   intx4;
typedef __attribute__((ext_vector_type(8))) int   intx8;    // 32B = one f8f6f4 K=128 operand
typedef unsigned char u8;
typedef unsigned int u32;
typedef unsigned long long u64;

// Address-space-qualified pointers for global_load_lds (hipcc does NOT
// implicitly convert generic pointers to AS(1)/AS(3) builtin params).
typedef const __attribute__((address_space(1))) u32 gas_u32;
typedef __attribute__((address_space(3))) u32 las_u32;
__device__ inline void stage16(const void* g, void* l) {
    __builtin_amdgcn_global_load_lds((gas_u32*)g, (las_u32*)l, 16, 0, 0);
}

// HW packed fp8 e4m3 convert: 4 floats -> 4 bytes (2x v_cvt_pk_fp8_f32)
__device__ inline u32 pk4(float x0, float x1, float x2, float x3) {
    int t = __builtin_amdgcn_cvt_pk_fp8_f32(x0, x1, 0, false);
    t = __builtin_amdgcn_cvt_pk_fp8_f32(x2, x3, t, true);
    return (u32)t;
}

__device__ inline float getc(const float4& f, int j) {
    return (j == 0) ? f.x : (j == 1) ? f.y : (j == 2) ? f.z : f.w;
}

// ---------------------------------------------------------------------------
// Fragment layout (split-half, ds_read-conflict-free): pixel p, channel c:
//   g = p>>4 (16-px slab), r = p&15, kb = c>>7, q = (c>>5)&3, h = (c>>4)&1,
//   e8 = c&15;  byte = g*4096 + kb*2048 + h*1024 + (q*16+r)*16 + e8
// Lane (q*16+r) of an MFMA operand assembles its 32 contiguous k-bytes from
// two 16B halves at +0/+1024 (lane-stride-16 b128 = conflict-free banking).
// A 64-col slice (4 slabs) is 16KB CONTIGUOUS -> linear global_load_lds.
//
// PREP: 512 blocks x 512 threads (16 waves/CU). Thread (pg=tid&7, tc=tid>>3)
// covers pixels pg*4..+3 (float4) x channels tc*4..+3 (one u32 frag store).
// Also zeroes packed/out (absorbs the two memset launches).
__global__ __launch_bounds__(512) void prep_kernel(const float* __restrict__ a,
                                                   const float* __restrict__ b,
                                                   float* __restrict__ sumsq_a,
                                                   float* __restrict__ sumsq_b,
                                                   u8* __restrict__ aF, u8* __restrict__ bF,
                                                   u64* __restrict__ packed,
                                                   float* __restrict__ out) {
    __shared__ float red[64][33];
    __shared__ float invb_sh[32];
    const int tid = threadIdx.x;
    const int pg = tid & 7, tc = tid >> 3;
    const int p0 = blockIdx.x * 32, pb = pg * 4;
    const int c0 = tc * 4;
    const u32 fb = (u32)((c0 >> 7) * 2048 + ((c0 >> 4) & 1) * 1024 + (c0 & 15));
    const u32 qr16 = (u32)(((c0 >> 5) & 3) * 16);   // q*16 (row offset added per pixel)

    if (blockIdx.x < 32) packed[(size_t)blockIdx.x * 512 + tid] = 0ull;
    if (blockIdx.x == 0 && tid == 0) *out = 0.f;

    // hoisted loads (8 independent float4 in flight)
    float4 bv[4], av[4];
    #pragma unroll
    for (int i = 0; i < 4; ++i)
        bv[i] = *(const float4*)&b[(size_t)(c0 + i) * HW + p0 + pb];
    #pragma unroll
    for (int i = 0; i < 4; ++i)
        av[i] = *(const float4*)&a[(size_t)(c0 + i) * HW + p0 + pb];

    float s0 = 0.f, s1 = 0.f, s2 = 0.f, s3 = 0.f;
    #pragma unroll
    for (int i = 0; i < 4; ++i) {
        s0 += bv[i].x * bv[i].x; s1 += bv[i].y * bv[i].y;
        s2 += bv[i].z * bv[i].z; s3 += bv[i].w * bv[i].w;
    }
    red[tc][pb] = s0; red[tc][pb + 1] = s1; red[tc][pb + 2] = s2; red[tc][pb + 3] = s3;
    __syncthreads();
    if (tid < 32) {
        float B = 0.f;
        #pragma unroll
        for (int j = 0; j < 64; ++j) B += red[j][tid];
        sumsq_b[p0 + tid] = B;
        invb_sh[tid] = 1.0f / (sqrtf(B + EPS) + EPS);
    }
    __syncthreads();

    // b fragment stores (normalized), one u32 per pixel
    #pragma unroll
    for (int j = 0; j < 4; ++j) {
        const int p = p0 + pb + j;
        const float inv = invb_sh[pb + j];
        u32 wv = pk4(getc(bv[0], j) * inv, getc(bv[1], j) * inv,
                     getc(bv[2], j) * inv, getc(bv[3], j) * inv);
        *(u32*)(bF + ((size_t)(p >> 4) << 12) + fb + (qr16 + (u32)(p & 15)) * 16) = wv;
    }

    // a: sumsq partials + raw fragment stores
    s0 = s1 = s2 = s3 = 0.f;
    #pragma unroll
    for (int i = 0; i < 4; ++i) {
        s0 += av[i].x * av[i].x; s1 += av[i].y * av[i].y;
        s2 += av[i].z * av[i].z; s3 += av[i].w * av[i].w;
    }
    red[tc][pb] = s0; red[tc][pb + 1] = s1; red[tc][pb + 2] = s2; red[tc][pb + 3] = s3;
    #pragma unroll
    for (int j = 0; j < 4; ++j) {
        const int p = p0 + pb + j;
        u32 wv = pk4(getc(av[0], j), getc(av[1], j), getc(av[2], j), getc(av[3], j));
        *(u32*)(aF + ((size_t)(p >> 4) << 12) + fb + (qr16 + (u32)(p & 15)) * 16) = wv;
    }
    __syncthreads();
    if (tid < 32) {
        float A = 0.f;
        #pragma unroll
        for (int j = 0; j < 64; ++j) A += red[j][tid];
        sumsq_a[p0 + tid] = A;
    }
}

// ---------------------------------------------------------------------------
// G: fused GEMM + argmax, MX-scaled fp8 (unit scales). Wave tile 64x32
// (2m x 2n waves). B is LDS-staged (R2 post-mortem: direct-from-L2 operand
// streaming hit the ~56 B/cy/CU L2 ceiling at MfmaUtil 35%): per qt one
// contiguous 16KB slice, double-buffered via global_load_lds width=16
// (4 instr/wave), 2-phase schedule {stage next | ds_read+mfma | argmax |
// barrier}. Halves L2 traffic (wm waves share LDS) and gives staging a full
// qt of latency cover. acc C-operand = {64,..} on kb=0 -> positive acc, no
// zeroing, raw-bit u64 pack at the end. Regs ~155 -> 3 waves/SIMD.
__global__ __launch_bounds__(256, 3) void gemm_argmax(const u8* __restrict__ aF,
                                                      const u8* __restrict__ bF,
                                                      u64* __restrict__ packed) {
    __shared__ u8 sB[2][16384];
    const int tid = threadIdx.x;
    const int w = tid >> 6, lane = tid & 63;
    const int q4 = lane >> 4, r15 = lane & 15;
    const int wm = w >> 1, wn = w & 1;

    const u32 bid = blockIdx.x;
    const u32 ng = bid & 7;          // n-group -> XCD (L2-resident B panel)
    const u32 mt = bid >> 3;         // 0..127 M tile
    const int p0 = (int)mt * BM;

    // A fragments resident: slab g = mt*8 + wm*4 + mi; two 16B halves at
    // g*4096 + kb*2048 + {0,1024} + lane*16
    const u8* gA = aF + (((size_t)(mt * 8 + wm * 4)) << 12) + (u32)lane * 16;
    intx8 Afr[4][2];
    #pragma unroll
    for (int mi = 0; mi < 4; ++mi)
        #pragma unroll
        for (int kb = 0; kb < 2; ++kb) {
            intx4 lo = *(const intx4*)(gA + (u32)(mi * 4096 + kb * 2048));
            intx4 hi = *(const intx4*)(gA + (u32)(mi * 4096 + kb * 2048 + 1024));
            Afr[mi][kb] = __builtin_shufflevector(lo, hi, 0, 1, 2, 3, 4, 5, 6, 7);
        }

    // B panel for this ng: qt slice = gQ + qt*16384, 16KB contiguous
    const u8* gQ = bF + ((size_t)ng << 19);
    const u32 so = (u32)w * 4096u + (u32)lane * 16u;    // stage src offset (per-lane)

    // prologue: stage qt=0 into buffer 0
    #pragma unroll
    for (int i = 0; i < 4; ++i)
        stage16(gQ + so + (u32)(i * 1024), &sB[0][w * 4096 + i * 1024]);

    float bestv[4][4];
    u32   bestq[4][4];
    #pragma unroll
    for (int mi = 0; mi < 4; ++mi)
        #pragma unroll
        for (int r = 0; r < 4; ++r) { bestv[mi][r] = -3.4e38f; bestq[mi][r] = 0; }

    u32 q0 = ng * 2048 + wn * 32 + (u32)r15;   // running col id (ni0); ni1 = +16
    const floatx4 C64 = {64.f, 64.f, 64.f, 64.f};
    const int SCL = 0x7F7F7F7F;      // E8M0 127 = 2^0 -> unit scale

    __syncthreads();                 // vmcnt(0) drain + barrier: buf0 ready

    int x = 0;
    for (int qt = 0; qt < 32; ++qt) {
        // stage qt+1 into the other buffer (loads span the whole compute phase)
        if (qt < 31) {
            const u8* gs = gQ + (u32)(qt + 1) * 16384u + so;
            u8* ls = &sB[x ^ 1][w * 4096];
            #pragma unroll
            for (int i = 0; i < 4; ++i)
                stage16(gs + (u32)(i * 1024), ls + i * 1024);
        }

        const u8* Lb = &sB[x][(u32)(wn * 2) * 4096u + (u32)lane * 16u];
        floatx4 acc[4][2];
        intx8 B0, B1;

        // kb = 0 (C = bias 64)
        { intx4 lo = *(const intx4*)(Lb);
          intx4 hi = *(const intx4*)(Lb + 1024);
          B0 = __builtin_shufflevector(lo, hi, 0, 1, 2, 3, 4, 5, 6, 7); }
        { intx4 lo = *(const intx4*)(Lb + 4096);
          intx4 hi = *(const intx4*)(Lb + 4096 + 1024);
          B1 = __builtin_shufflevector(lo, hi, 0, 1, 2, 3, 4, 5, 6, 7); }
        __builtin_amdgcn_s_setprio(1);
        #pragma unroll
        for (int mi = 0; mi < 4; ++mi)
            acc[mi][0] = __builtin_amdgcn_mfma_scale_f32_16x16x128_f8f6f4(
                Afr[mi][0], B0, C64, 0, 0, 0, SCL, 0, SCL);
        #pragma unroll
        for (int mi = 0; mi < 4; ++mi)
            acc[mi][1] = __builtin_amdgcn_mfma_scale_f32_16x16x128_f8f6f4(
                Afr[mi][0], B1, C64, 0, 0, 0, SCL, 0, SCL);
        __builtin_amdgcn_s_setprio(0);

        // kb = 1 (accumulate)
        { intx4 lo = *(const intx4*)(Lb + 2048);
          intx4 hi = *(const intx4*)(Lb + 2048 + 1024);
          B0 = __builtin_shufflevector(lo, hi, 0, 1, 2, 3, 4, 5, 6, 7); }
        { intx4 lo = *(const intx4*)(Lb + 4096 + 2048);
          intx4 hi = *(const intx4*)(Lb + 4096 + 2048 + 1024);
          B1 = __builtin_shufflevector(lo, hi, 0, 1, 2, 3, 4, 5, 6, 7); }
        __builtin_amdgcn_s_setprio(1);
        #pragma unroll
        for (int mi = 0; mi < 4; ++mi)
            acc[mi][0] = __builtin_amdgcn_mfma_scale_f32_16x16x128_f8f6f4(
                Afr[mi][1], B0, acc[mi][0], 0, 0, 0, SCL, 0, SCL);
        #pragma unroll
        for (int mi = 0; mi < 4; ++mi)
            acc[mi][1] = __builtin_amdgcn_mfma_scale_f32_16x16x128_f8f6f4(
                Afr[mi][1], B1, acc[mi][1], 0, 0, 0, SCL, 0, SCL);
        __builtin_amdgcn_s_setprio(0);

        // running argmax (ascending q scan, strict > keeps first = smallest q)
        #pragma unroll
        for (int mi = 0; mi < 4; ++mi)
            #pragma unroll
            for (int r = 0; r < 4; ++r) {
                float v = acc[mi][0][r];
                bool gt = v > bestv[mi][r];
                bestv[mi][r] = gt ? v : bestv[mi][r];
                bestq[mi][r] = gt ? q0 : bestq[mi][r];
            }
        #pragma unroll
        for (int mi = 0; mi < 4; ++mi)
            #pragma unroll
            for (int r = 0; r < 4; ++r) {
                float v = acc[mi][1][r];
                bool gt = v > bestv[mi][r];
                bestv[mi][r] = gt ? v : bestv[mi][r];
                bestq[mi][r] = gt ? (q0 + 16u) : bestq[mi][r];
            }
        q0 += 64u;

        __syncthreads();             // staged buffer landed; all reads of sB[x] done
        x ^= 1;
    }

    // final: pack (acc = s+64 > 0 -> float bits monotone as uint),
    // shuffle-reduce over r15 (stays in q4 group), 1 atomic/row/wave
    #pragma unroll
    for (int mi = 0; mi < 4; ++mi)
        #pragma unroll
        for (int r = 0; r < 4; ++r) {
            u64 pk = ((u64)__float_as_uint(bestv[mi][r]) << 32)
                   | (u64)(0xFFFFFFFFu - bestq[mi][r]);
            #pragma unroll
            for (int d = 1; d < 16; d <<= 1) {
                u64 o = __shfl_xor((unsigned long long)pk, d);
                pk = o > pk ? o : pk;
            }
            if (r15 == 0)
                atomicMax(&packed[p0 + wm * 64 + mi * 16 + q4 * 4 + r], pk);
        }
}

// ---------------------------------------------------------------------------
// L: loss from the argmax's own similarity value (no gather).
// Decode: hi = bits(s+64) -> s = asfloat(hi) - 64; lo = ~q.
__global__ void loss_kernel(const u64* __restrict__ packed,
                            const float* __restrict__ sumsq_a, const float* __restrict__ sumsq_b,
                            float* __restrict__ out) {
    int p = blockIdx.x * 256 + threadIdx.x;
    u64 pk = packed[p];
    float s = __uint_as_float((u32)(pk >> 32)) - 64.0f;
    u32 q = 0xFFFFFFFFu - (u32)(pk & 0xFFFFFFFFull);
    float A = sumsq_a[p], B = sumsq_b[q];
    float dot = s * (sqrtf(B + EPS) + EPS);
    float cossim = dot / ((sqrtf(A) + EPS) * (sqrtf(B) + EPS));
    float v = (1.0f - cossim) * (1.0f / (float)HW);
    #pragma unroll
    for (int d = 1; d < 64; d <<= 1) v += __shfl_xor(v, d);
    if ((threadIdx.x & 63) == 0) atomicAdd(out, v);
}

// ---------------------------------------------------------------------------
extern "C" void kernel_launch(void* const* d_in, const int* in_sizes, int n_in,
                              void* d_out, int out_size, void* d_ws, size_t ws_size,
                              hipStream_t stream) {
    const float* a = (const float*)d_in[0];
    const float* b = (const float*)d_in[1];
    float* out = (float*)d_out;
    char* ws = (char*)d_ws;

    u8*    aF      = (u8*)ws;                                    // 4 MB
    u8*    bF      = (u8*)(ws + (size_t)4 * 1024 * 1024);        // 4 MB
    float* sumsq_a = (float*)(ws + (size_t)8 * 1024 * 1024);     // 64 KB
    float* sumsq_b = sumsq_a + HW;
    u64*   packed  = (u64*)(sumsq_b + HW);                       // 128 KB

    prep_kernel<<<dim3(HW / 32), 512, 0, stream>>>(a, b, sumsq_a, sumsq_b, aF, bF, packed, out);
    gemm_argmax<<<dim3((HW / BM) * (HW / NG)), 256, 0, stream>>>(aF, bF, packed);
    loss_kernel<<<dim3(HW / 256), 256, 0, stream>>>(packed, sumsq_a, sumsq_b, out);
}